// Round 1
// 144.070 us; speedup vs baseline: 1.0056x; 1.0056x over previous
//
#include <hip/hip_runtime.h>

// DistributionLoss: local 7x7xC std (zero-padded) of two [16,3,512,512] fp32
// tensors, smooth-L1 mean between std maps -> scalar.
//
// R8: fused-input single-barrier design.
//  - ONE Phase A covers BOTH inputs (task space 2 x HR x 8); interior
//    barriers drop 4 -> 1. Smooth-L1 is computed inline in Phase B (no
//    cross-barrier register parking).
//  - Tasks widened to 8 output columns (12 float4 loads: A | B | B2 | C):
//    channel add3/sq3 redundancy drops 18->12 quads per 8 px, horizontal
//    7-tap slide amortizes to 14 adds per 8 cols.
//  - LDSW 68->64: fused LDS = 38.9 KB -> 4 blocks/CU. Stride 64 floats is a
//    BALANCED bank pattern for both the Phase A writes and Phase B b128
//    reads (8 requests/bank across the wave = minimum cycles, not a
//    conflict), so the +4 pad is dead weight here.
//  - Phase B unchanged 2-rows-per-thread vertical slide (S2 = S - top + bot).

#define K     7
#define PAD   3
#define TSX   64
#define TSY   32
#define HR    (TSY + K - 1)   // 38 halo rows
#define LDSW  64              // LDS row stride (floats)
#define NT    256
#define NTASK (2 * HR * 8)    // 608 fused tasks (both inputs)

__device__ __forceinline__ float4 add3(float4 a, float4 b, float4 c) {
    return make_float4(a.x + b.x + c.x, a.y + b.y + c.y,
                       a.z + b.z + c.z, a.w + b.w + c.w);
}
__device__ __forceinline__ float4 sq3(float4 a, float4 b, float4 c) {
    return make_float4(fmaf(a.x, a.x, fmaf(b.x, b.x, c.x * c.x)),
                       fmaf(a.y, a.y, fmaf(b.y, b.y, c.y * c.y)),
                       fmaf(a.z, a.z, fmaf(b.z, b.z, c.z * c.z)),
                       fmaf(a.w, a.w, fmaf(b.w, b.w, c.w * c.w)));
}

__global__ __launch_bounds__(NT, 4) void dist_loss_kernel(
    const float* __restrict__ pred,
    const float* __restrict__ tgt,
    float* __restrict__ out)
{
    constexpr int   C = 3, H = 512, W = 512;
    constexpr float INV_N     = 1.0f / (C * K * K);              // 1/147
    constexpr float INV_TOTAL = 1.0f / (16.0f * 512.0f * 512.0f);

    __shared__ float sh_s[2][HR][LDSW];   // horizontal 7-tap of channel sum
    __shared__ float sh_q[2][HR][LDSW];   // horizontal 7-tap of channel sum-sq

    const int    tid  = threadIdx.x;
    const int    tx0  = blockIdx.x * TSX;
    const int    ty0  = blockIdx.y * TSY;
    const int    b    = blockIdx.z;
    const size_t plane = (size_t)H * W;
    const float4 z4 = make_float4(0.f, 0.f, 0.f, 0.f);

    const float* base0 = pred + (size_t)b * C * plane;
    const float* base1 = tgt  + (size_t)b * C * plane;

    // ---- Phase A (both inputs): global -> horizontal 7-tap -> LDS (h, g)
    for (int task = tid; task < NTASK; task += NT) {
        const int   which = (task >= HR * 8) ? 1 : 0;
        const int   t     = which ? task - HR * 8 : task;
        const int   row = t >> 3;                    // 0..37
        const int   cg  = t & 7;                     // 8-col group
        const int   gy  = ty0 - PAD + row;
        const float m   = ((unsigned)gy < (unsigned)H) ? 1.0f : 0.0f;
        const int   gyc = min(max(gy, 0), H - 1);    // loads always legal
        const int   gx0 = tx0 + (cg << 3);
        const bool  leftOK  = (gx0 > 0);
        const bool  rightOK = (gx0 < 504);           // C quad at gx0+8..+11

        const float* base = which ? base1 : base0;
        const float* r0 = base + (size_t)gyc * W + gx0;
        const float* r1 = r0 + plane;
        const float* r2 = r1 + plane;

        float4 A0 = leftOK  ? *(const float4*)(r0 - 4) : z4;
        float4 B0 = *(const float4*)(r0);
        float4 D0 = *(const float4*)(r0 + 4);
        float4 E0 = rightOK ? *(const float4*)(r0 + 8) : z4;
        float4 A1 = leftOK  ? *(const float4*)(r1 - 4) : z4;
        float4 B1 = *(const float4*)(r1);
        float4 D1 = *(const float4*)(r1 + 4);
        float4 E1 = rightOK ? *(const float4*)(r1 + 8) : z4;
        float4 A2 = leftOK  ? *(const float4*)(r2 - 4) : z4;
        float4 B2 = *(const float4*)(r2);
        float4 D2 = *(const float4*)(r2 + 4);
        float4 E2 = rightOK ? *(const float4*)(r2 + 8) : z4;

        float4 tl = add3(A0, A1, A2);   // cols -4..-1 (y,z,w used)
        float4 ta = add3(B0, B1, B2);   // cols  0..3
        float4 tb = add3(D0, D1, D2);   // cols  4..7
        float4 tr = add3(E0, E1, E2);   // cols  8..11 (x,y,z used)
        float4 ul = sq3(A0, A1, A2);
        float4 ua = sq3(B0, B1, B2);
        float4 ub = sq3(D0, D1, D2);
        float4 ur = sq3(E0, E1, E2);

        // sliding 7-tap horizontal window, 8 output cols
        float h0 = tl.y + tl.z + tl.w + ta.x + ta.y + ta.z + ta.w;
        float h1 = h0 - tl.y + tb.x;
        float h2 = h1 - tl.z + tb.y;
        float h3 = h2 - tl.w + tb.z;
        float h4 = h3 - ta.x + tb.w;
        float h5 = h4 - ta.y + tr.x;
        float h6 = h5 - ta.z + tr.y;
        float h7 = h6 - ta.w + tr.z;

        float g0 = ul.y + ul.z + ul.w + ua.x + ua.y + ua.z + ua.w;
        float g1 = g0 - ul.y + ub.x;
        float g2 = g1 - ul.z + ub.y;
        float g3 = g2 - ul.w + ub.z;
        float g4 = g3 - ua.x + ub.w;
        float g5 = g4 - ua.y + ur.x;
        float g6 = g5 - ua.z + ur.y;
        float g7 = g6 - ua.w + ur.z;

        float* ps = &sh_s[which][row][cg << 3];
        float* pq = &sh_q[which][row][cg << 3];
        *(float4*)(ps)     = make_float4(h0 * m, h1 * m, h2 * m, h3 * m);
        *(float4*)(ps + 4) = make_float4(h4 * m, h5 * m, h6 * m, h7 * m);
        *(float4*)(pq)     = make_float4(g0 * m, g1 * m, g2 * m, g3 * m);
        *(float4*)(pq + 4) = make_float4(g4 * m, g5 * m, g6 * m, g7 * m);
    }
    __syncthreads();

    // ---- Phase B: vertical 7-tap + std + fused smooth-L1; 2 rows/thread
    float acc = 0.0f;
    {
        const int rp = tid >> 4;          // row pair 0..15
        const int x  = (tid & 15) << 2;   // col within tile

        float4 pA, pB;                    // input 0 std quads

        #define STD4(Sv, Qv, D)                                           \
            {                                                             \
                float mux = (Sv).x * INV_N, muy = (Sv).y * INV_N,         \
                      muz = (Sv).z * INV_N, muw = (Sv).w * INV_N;         \
                (D).x = sqrtf(fmaf(-mux, mux, (Qv).x * INV_N) + 1e-8f);   \
                (D).y = sqrtf(fmaf(-muy, muy, (Qv).y * INV_N) + 1e-8f);   \
                (D).z = sqrtf(fmaf(-muz, muz, (Qv).z * INV_N) + 1e-8f);   \
                (D).w = sqrtf(fmaf(-muw, muw, (Qv).w * INV_N) + 1e-8f);   \
            }
        #define SL1(a, bb)                                                \
            {                                                             \
                float d  = (a) - (bb);                                    \
                float ad = fabsf(d);                                      \
                acc += (ad < 1.0f) ? 0.5f * d * d : (ad - 0.5f);          \
            }

        #pragma unroll
        for (int w = 0; w < 2; ++w) {
            float4 S = z4, Q = z4;
            #pragma unroll
            for (int k = 0; k < K; ++k) {
                float4 hv = *(const float4*)&sh_s[w][2 * rp + k][x];
                float4 gv = *(const float4*)&sh_q[w][2 * rp + k][x];
                S.x += hv.x; S.y += hv.y; S.z += hv.z; S.w += hv.w;
                Q.x += gv.x; Q.y += gv.y; Q.z += gv.z; Q.w += gv.w;
            }
            float4 hA = *(const float4*)&sh_s[w][2 * rp][x];
            float4 gA = *(const float4*)&sh_q[w][2 * rp][x];
            float4 hB = *(const float4*)&sh_s[w][2 * rp + 7][x];
            float4 gB = *(const float4*)&sh_q[w][2 * rp + 7][x];
            float4 S2 = make_float4(S.x - hA.x + hB.x, S.y - hA.y + hB.y,
                                    S.z - hA.z + hB.z, S.w - hA.w + hB.w);
            float4 Q2 = make_float4(Q.x - gA.x + gB.x, Q.y - gA.y + gB.y,
                                    Q.z - gA.z + gB.z, Q.w - gA.w + gB.w);

            if (w == 0) {
                STD4(S, Q, pA);
                STD4(S2, Q2, pB);
            } else {
                float4 sA, sB;
                STD4(S, Q, sA);
                STD4(S2, Q2, sB);
                SL1(pA.x, sA.x); SL1(pA.y, sA.y);
                SL1(pA.z, sA.z); SL1(pA.w, sA.w);
                SL1(pB.x, sB.x); SL1(pB.y, sB.y);
                SL1(pB.z, sB.z); SL1(pB.w, sB.w);
            }
        }
        #undef STD4
        #undef SL1
    }

    // ---- block reduction: wave64 shuffle, cross-wave via LDS, one atomic
    #pragma unroll
    for (int off = 32; off > 0; off >>= 1)
        acc += __shfl_down(acc, off, 64);

    __shared__ float wave_sums[NT / 64];
    if ((tid & 63) == 0) wave_sums[tid >> 6] = acc;
    __syncthreads();
    if (tid == 0) {
        float s = 0.0f;
        #pragma unroll
        for (int w = 0; w < NT / 64; ++w) s += wave_sums[w];
        atomicAdd(out, s * INV_TOTAL);
    }
}

extern "C" void kernel_launch(void* const* d_in, const int* in_sizes, int n_in,
                              void* d_out, int out_size, void* d_ws, size_t ws_size,
                              hipStream_t stream) {
    const float* pred = (const float*)d_in[0];
    const float* tgt  = (const float*)d_in[1];
    float* out = (float*)d_out;

    hipMemsetAsync(out, 0, sizeof(float), stream);

    dim3 grid(512 / TSX, 512 / TSY, 16);   // 8 x 16 x 16 = 2048 blocks
    dist_loss_kernel<<<grid, NT, 0, stream>>>(pred, tgt, out);
}